// Round 7
// baseline (848.024 us; speedup 1.0000x reference)
//
#include <hip/hip_runtime.h>
#include <hip/hip_bf16.h>

using bf16x8 = __attribute__((ext_vector_type(8))) short;
using f32x4  = __attribute__((ext_vector_type(4))) float;

static constexpr int NN = 2048;   // nodes
static constexpr int NB = 32;     // batch
static constexpr int NC = 32;     // channels (C1 == C2)

__device__ __forceinline__ unsigned short f2bf(float f) {
    unsigned int u = __float_as_uint(f);
    u += 0x7FFFu + ((u >> 16) & 1u);   // round-to-nearest-even
    return (unsigned short)(u >> 16);
}

// Deep-prefetch GEMM tile body: 16 rows x 32 cols per wave, full K=2048.
// Per 128-float visit: 8 dwordx4 A-loads in flight (~4KB/wave) so 4 waves/CU
// still covers BW*latency. A converted in-register via v_cvt_pk_bf16_f32.
__device__ __forceinline__ void gemm_tile_deep(
    const float* __restrict__ ap,          // &A[b][r0+wave*16+lr][kg*8]
    const unsigned short* __restrict__ bp0,// &Bt[b][lr][kg*8]
    f32x4& acc0, f32x4& acc1)
{
    const unsigned short* bp1 = bp0 + (size_t)16 * NN;
    union ABf { bf16x8 v; __hip_bfloat16 e[8]; };
    for (int k = 0; k < NN; k += 128) {
        float4 xa[8]; bf16x8 bb0[4], bb1[4];
#pragma unroll
        for (int s = 0; s < 4; ++s) {
            xa[2 * s]     = *reinterpret_cast<const float4*>(ap + s * 32);
            xa[2 * s + 1] = *reinterpret_cast<const float4*>(ap + s * 32 + 4);
            bb0[s] = *reinterpret_cast<const bf16x8*>(bp0 + s * 32);
            bb1[s] = *reinterpret_cast<const bf16x8*>(bp1 + s * 32);
        }
        ap += 128; bp0 += 128; bp1 += 128;
#pragma unroll
        for (int s = 0; s < 4; ++s) {
            ABf af;
            af.e[0] = __float2bfloat16(xa[2 * s].x);
            af.e[1] = __float2bfloat16(xa[2 * s].y);
            af.e[2] = __float2bfloat16(xa[2 * s].z);
            af.e[3] = __float2bfloat16(xa[2 * s].w);
            af.e[4] = __float2bfloat16(xa[2 * s + 1].x);
            af.e[5] = __float2bfloat16(xa[2 * s + 1].y);
            af.e[6] = __float2bfloat16(xa[2 * s + 1].z);
            af.e[7] = __float2bfloat16(xa[2 * s + 1].w);
            acc0 = __builtin_amdgcn_mfma_f32_16x16x32_bf16(af.v, bb0[s], acc0, 0, 0, 0);
            acc1 = __builtin_amdgcn_mfma_f32_16x16x32_bf16(af.v, bb1[s], acc1, 0, 0, 0);
        }
    }
}

// ---------------------------------------------------------------------------
// Cooperative fused GCN: grid = 256 blocks (1/CU), 4 iterations x 8 batches.
// Iteration: phase0 proj1 (64-row slice) -> ctr; phase1 gemm1+fused proj2
// -> ctr; phase2 gemm2+pool.  gemm2 re-reads the A[b] (16MB) that phase1
// streamed moments earlier: 8 batches in flight = 128MB working set << 256MB
// memory-side L3, so the second A pass is served from Infinity Cache.
// Per-batch counters + device-scope fences; co-residency (cooperative launch)
// makes spin-waits deadlock-free; the dependency graph is acyclic.
// ---------------------------------------------------------------------------
__global__ __launch_bounds__(256, 1)
void fused_gcn(const float* __restrict__ A, const float* __restrict__ X,
               const float* __restrict__ W1, const float* __restrict__ b1,
               const float* __restrict__ W2, const float* __restrict__ b2,
               unsigned short* __restrict__ xwt1, unsigned short* __restrict__ xwt2,
               float* __restrict__ pooled,
               unsigned int* __restrict__ done0, unsigned int* __restrict__ done1)
{
    __shared__ float smem[64 * 33 + 1024];   // h-tile (64x33) + W2 (1024) / W1 (2048)

    const int t    = threadIdx.x;
    const int g    = blockIdx.x;          // 0..255
    const int tile = g & 31;
    const int r0   = tile * 64;
    const int wave = t >> 6, lane = t & 63;
    const int lr   = lane & 15, kg = lane >> 4;

    for (int it = 0; it < 4; ++it) {
        const int b = it * 8 + (g >> 5);

        // ---------------- phase 0: proj1 rows r0..r0+63 ----------------
        __syncthreads();
        for (int i = t; i < 64 * 32; i += 256) smem[i] = W1[i];
        __syncthreads();
        {
            const int row = r0 + (t >> 2);
            const int c0  = (t & 3) * 8;
            const float* xrow = X + ((size_t)b * NN + row) * 64;
            float acc[8] = {0.f, 0.f, 0.f, 0.f, 0.f, 0.f, 0.f, 0.f};
            for (int f = 0; f < 64; ++f) {
                const float xv = xrow[f];
#pragma unroll
                for (int i = 0; i < 8; ++i) acc[i] += xv * smem[f * 32 + c0 + i];
            }
            unsigned short* op = xwt1 + (size_t)b * NC * NN + row;
#pragma unroll
            for (int i = 0; i < 8; ++i) op[(size_t)(c0 + i) * NN] = f2bf(acc[i]);
        }
        __threadfence();
        __syncthreads();
        if (t == 0) {
            atomicAdd(&done0[b], 1u);
            while (atomicAdd(&done0[b], 0u) < 32u) __builtin_amdgcn_s_sleep(2);
        }
        __syncthreads();
        __threadfence();

        // ---------------- phase 1: gemm1 + fused proj2 ----------------
        f32x4 acc0 = {0.f, 0.f, 0.f, 0.f};
        f32x4 acc1 = {0.f, 0.f, 0.f, 0.f};
        gemm_tile_deep(A + ((size_t)b * NN + r0 + wave * 16 + lr) * NN + kg * 8,
                       xwt1 + (size_t)b * NC * NN + (size_t)lr * NN + kg * 8,
                       acc0, acc1);
        {
            float* hl  = smem;             // 64 x 33
            float* w2l = smem + 64 * 33;   // 32 x 32
            const float bb0 = b1[lr], bb1 = b1[lr + 16];
#pragma unroll
            for (int j = 0; j < 4; ++j) {
                const int rr = wave * 16 + kg * 4 + j;
                hl[rr * 33 + lr]      = fmaxf(acc0[j] + bb0, 0.f);
                hl[rr * 33 + lr + 16] = fmaxf(acc1[j] + bb1, 0.f);
            }
            *reinterpret_cast<float4*>(&w2l[t * 4]) =
                *reinterpret_cast<const float4*>(&W2[t * 4]);
            __syncthreads();
            const int m  = t >> 2;
            const int c0 = (t & 3) * 8;
            float o[8] = {0.f, 0.f, 0.f, 0.f, 0.f, 0.f, 0.f, 0.f};
            for (int c = 0; c < 32; ++c) {
                const float hv = hl[m * 33 + c];
#pragma unroll
                for (int i = 0; i < 8; ++i) o[i] += hv * w2l[c * 32 + c0 + i];
            }
            unsigned short* op = xwt2 + (size_t)b * NC * NN + r0 + m;
#pragma unroll
            for (int i = 0; i < 8; ++i) op[(size_t)(c0 + i) * NN] = f2bf(o[i]);
        }
        __threadfence();
        __syncthreads();
        if (t == 0) {
            atomicAdd(&done1[b], 1u);
            while (atomicAdd(&done1[b], 0u) < 32u) __builtin_amdgcn_s_sleep(2);
        }
        __syncthreads();
        __threadfence();

        // ---------------- phase 2: gemm2 + global sum-pool ----------------
        acc0 = f32x4{0.f, 0.f, 0.f, 0.f};
        acc1 = f32x4{0.f, 0.f, 0.f, 0.f};
        gemm_tile_deep(A + ((size_t)b * NN + r0 + wave * 16 + lr) * NN + kg * 8,
                       xwt2 + (size_t)b * NC * NN + (size_t)lr * NN + kg * 8,
                       acc0, acc1);
        {
            const float bb0 = b2[lr], bb1 = b2[lr + 16];
            float s0 = 0.f, s1 = 0.f;
#pragma unroll
            for (int j = 0; j < 4; ++j) {
                s0 += fmaxf(acc0[j] + bb0, 0.f);
                s1 += fmaxf(acc1[j] + bb1, 0.f);
            }
            s0 += __shfl_xor(s0, 16); s0 += __shfl_xor(s0, 32);
            s1 += __shfl_xor(s1, 16); s1 += __shfl_xor(s1, 32);
            if (kg == 0) {
                atomicAdd(&pooled[b * NC + lr],      s0);
                atomicAdd(&pooled[b * NC + 16 + lr], s1);
            }
        }
    }
}

// ---------------------------------------------------------------------------
// FC head: out[b] = sum_h relu(pooled[b,:] @ Wf1[:,h] + bf1[h]) * Wf2[h] + bf2
// ---------------------------------------------------------------------------
__global__ void head_kernel(const float* __restrict__ pooled,
                            const float* __restrict__ Wf1, const float* __restrict__ bf1,
                            const float* __restrict__ Wf2, const float* __restrict__ bf2,
                            float* __restrict__ out)
{
    const int b = blockIdx.x;
    const int h = threadIdx.x;   // 0..511

    float dot = 0.f;
#pragma unroll
    for (int c = 0; c < NC; ++c)
        dot += pooled[b * NC + c] * Wf1[c * 512 + h];

    const float v = fmaxf(dot + bf1[h], 0.f);
    float part    = v * Wf2[h];

#pragma unroll
    for (int off = 32; off >= 1; off >>= 1)
        part += __shfl_xor(part, off);

    __shared__ float red[8];
    if ((threadIdx.x & 63) == 0) red[threadIdx.x >> 6] = part;
    __syncthreads();
    if (threadIdx.x == 0) {
        float s = 0.f;
#pragma unroll
        for (int i = 0; i < 8; ++i) s += red[i];
        out[b] = s + bf2[0];
    }
}

// ---------------------------------------------------------------------------
extern "C" void kernel_launch(void* const* d_in, const int* in_sizes, int n_in,
                              void* d_out, int out_size, void* d_ws, size_t ws_size,
                              hipStream_t stream)
{
    const float* x   = (const float*)d_in[0];
    const float* a   = (const float*)d_in[1];
    const float* W1  = (const float*)d_in[2];
    const float* b1  = (const float*)d_in[3];
    const float* W2  = (const float*)d_in[4];
    const float* b2  = (const float*)d_in[5];
    const float* Wf1 = (const float*)d_in[6];
    const float* bf1 = (const float*)d_in[7];
    const float* Wf2 = (const float*)d_in[8];
    const float* bf2 = (const float*)d_in[9];
    float* out = (float*)d_out;

    char* ws = (char*)d_ws;
    float*          pooled = (float*)ws;                              // 4 KB
    unsigned int*   done0  = (unsigned int*)(ws + 4096);              // 128 B
    unsigned int*   done1  = (unsigned int*)(ws + 4096 + 256);        // 128 B
    unsigned short* xwt1   = (unsigned short*)(ws + (1ull << 20));    // 4 MB
    unsigned short* xwt2   = (unsigned short*)(ws + (5ull << 20));    // 4 MB

    // zero pooled + counters (captured; re-runs on every replay)
    hipMemsetAsync(ws, 0, 8192, stream);

    void* args[] = {(void*)&a, (void*)&x, (void*)&W1, (void*)&b1, (void*)&W2,
                    (void*)&b2, (void*)&xwt1, (void*)&xwt2, (void*)&pooled,
                    (void*)&done0, (void*)&done1};
    hipLaunchCooperativeKernel((const void*)fused_gcn, dim3(256), dim3(256),
                               args, 0, stream);

    head_kernel<<<dim3(NB), 512, 0, stream>>>(pooled, Wf1, bf1, Wf2, bf2, out);
}

// Round 8
// 327.000 us; speedup vs baseline: 2.5933x; 2.5933x over previous
//
#include <hip/hip_runtime.h>
#include <hip/hip_bf16.h>

using bf16x8 = __attribute__((ext_vector_type(8))) short;
using f32x4  = __attribute__((ext_vector_type(4))) float;

static constexpr int NN = 2048;   // nodes
static constexpr int NB = 32;     // batch
static constexpr int NC = 32;     // channels (C1 == C2)
static constexpr int GB = 8;      // batches per L3 chunk (A-chunk = 128 MB << 256 MB L3)

__device__ __forceinline__ unsigned short f2bf(float f) {
    unsigned int u = __float_as_uint(f);
    u += 0x7FFFu + ((u >> 16) & 1u);   // round-to-nearest-even
    return (unsigned short)(u >> 16);
}

// ---------------------------------------------------------------------------
// Projection: XWt[b][c][m] = bf16( sum_f X[b][m][f] * W[f][c] )   (no bias/relu)
// grid = (NN/256, NB), block = 256. One thread per node-row m.
// ---------------------------------------------------------------------------
template<int INCH>
__global__ void proj_kernel(const float* __restrict__ X, const float* __restrict__ W,
                            unsigned short* __restrict__ XWt)
{
    __shared__ float wlds[INCH * NC];
    const int b = blockIdx.y;
    const int m = blockIdx.x * 256 + threadIdx.x;
    for (int i = threadIdx.x; i < INCH * NC; i += 256) wlds[i] = W[i];
    __syncthreads();

    const float* xrow = X + ((size_t)b * NN + m) * INCH;
    float acc[NC];
#pragma unroll
    for (int c = 0; c < NC; ++c) acc[c] = 0.f;

    for (int f = 0; f < INCH; f += 4) {
        const float4 v = *reinterpret_cast<const float4*>(xrow + f);
        const float xv[4] = {v.x, v.y, v.z, v.w};
#pragma unroll
        for (int j = 0; j < 4; ++j) {
#pragma unroll
            for (int c = 0; c < NC; ++c)
                acc[c] += xv[j] * wlds[(f + j) * NC + c];
        }
    }

    unsigned short* outp = XWt + (size_t)b * NC * NN + m;
#pragma unroll
    for (int c = 0; c < NC; ++c) outp[(size_t)c * NN] = f2bf(acc[c]);
}

// ---------------------------------------------------------------------------
// K-split GCN GEMM (chunked-batch mode). Block = 256 thr (4 waves), 16 output
// rows, 32 cols. Wave w covers K in [w*512, w*512+512) with the deep-prefetch
// body (8 dwordx4 A-loads in flight); cross-wave K-reduction via padded LDS.
// grid = (NN/16, GB) = 1024 blocks -> 4 blocks/CU, 16 waves/CU (same
// occupancy as the 289us baseline, but batch-chunked so the second A pass
// (next dispatch) is served from Infinity Cache: chunk = 128MB << 256MB L3,
// proven by round-7's FETCH_SIZE=553MB coop kernel).
// FUSE=true : epilogue xwt2 = relu(acc+b1) @ W2  (layer1 + proj2 fused)
// FUSE=false: epilogue relu(acc+b2) column-sum -> atomicAdd pooled (layer2+pool)
// ---------------------------------------------------------------------------
template<bool FUSE>
__global__ __launch_bounds__(256, 4)
void gcn_gemm_ks(const float* __restrict__ A, const unsigned short* __restrict__ Bt,
                 const float* __restrict__ bias, const float* __restrict__ W2,
                 unsigned short* __restrict__ XWt2, float* __restrict__ pooled,
                 int bbase)
{
    __shared__ float red[3][16][33];   // K-partials of waves 1..3 (pad 33: no bank conflict)
    __shared__ float hl[16][33];       // relu'd h tile (FUSE epilogue)
    __shared__ float w2l[32 * 32];     // W2 (FUSE epilogue)

    const int b    = bbase + blockIdx.y;
    const int t    = threadIdx.x;
    const int w    = t >> 6, lane = t & 63;
    const int lr   = lane & 15, kg = lane >> 4;
    const int r0   = blockIdx.x * 16;

    if constexpr (FUSE) {
        *reinterpret_cast<float4*>(&w2l[t * 4]) =
            *reinterpret_cast<const float4*>(&W2[t * 4]);
    }

    const float*          ap  = A  + ((size_t)b * NN + r0 + lr) * NN + w * 512 + kg * 8;
    const unsigned short* bp0 = Bt + ((size_t)b * NC + lr) * NN + w * 512 + kg * 8;
    const unsigned short* bp1 = bp0 + (size_t)16 * NN;

    f32x4 acc0 = {0.f, 0.f, 0.f, 0.f};
    f32x4 acc1 = {0.f, 0.f, 0.f, 0.f};
    union ABf { bf16x8 v; __hip_bfloat16 e[8]; };

    for (int k = 0; k < 512; k += 128) {
        float4 xa[8]; bf16x8 bb0[4], bb1[4];
#pragma unroll
        for (int s = 0; s < 4; ++s) {
            xa[2 * s]     = *reinterpret_cast<const float4*>(ap + s * 32);
            xa[2 * s + 1] = *reinterpret_cast<const float4*>(ap + s * 32 + 4);
            bb0[s] = *reinterpret_cast<const bf16x8*>(bp0 + s * 32);
            bb1[s] = *reinterpret_cast<const bf16x8*>(bp1 + s * 32);
        }
        ap += 128; bp0 += 128; bp1 += 128;
#pragma unroll
        for (int s = 0; s < 4; ++s) {
            ABf af;
            af.e[0] = __float2bfloat16(xa[2 * s].x);
            af.e[1] = __float2bfloat16(xa[2 * s].y);
            af.e[2] = __float2bfloat16(xa[2 * s].z);
            af.e[3] = __float2bfloat16(xa[2 * s].w);
            af.e[4] = __float2bfloat16(xa[2 * s + 1].x);
            af.e[5] = __float2bfloat16(xa[2 * s + 1].y);
            af.e[6] = __float2bfloat16(xa[2 * s + 1].z);
            af.e[7] = __float2bfloat16(xa[2 * s + 1].w);
            acc0 = __builtin_amdgcn_mfma_f32_16x16x32_bf16(af.v, bb0[s], acc0, 0, 0, 0);
            acc1 = __builtin_amdgcn_mfma_f32_16x16x32_bf16(af.v, bb1[s], acc1, 0, 0, 0);
        }
    }

    // ----- cross-wave K reduction (C/D map: row = kg*4+j, col = lr / lr+16) -----
    if (w > 0) {
#pragma unroll
        for (int j = 0; j < 4; ++j) {
            red[w - 1][kg * 4 + j][lr]      = acc0[j];
            red[w - 1][kg * 4 + j][lr + 16] = acc1[j];
        }
    }
    __syncthreads();

    if constexpr (FUSE) {
        if (w == 0) {
            const float bb0v = bias[lr], bb1v = bias[lr + 16];
#pragma unroll
            for (int j = 0; j < 4; ++j) {
                const int row = kg * 4 + j;
                float a0 = acc0[j], a1 = acc1[j];
#pragma unroll
                for (int ww = 0; ww < 3; ++ww) {
                    a0 += red[ww][row][lr];
                    a1 += red[ww][row][lr + 16];
                }
                hl[row][lr]      = fmaxf(a0 + bb0v, 0.f);
                hl[row][lr + 16] = fmaxf(a1 + bb1v, 0.f);
            }
        }
        __syncthreads();
        // proj2: all 256 threads; thread -> (row = t>>4, 2 channels c0, c0+1)
        const int row = t >> 4;
        const int c0  = (t & 15) * 2;
        float o0 = 0.f, o1 = 0.f;
#pragma unroll
        for (int c = 0; c < 32; ++c) {
            const float hv = hl[row][c];
            o0 += hv * w2l[c * 32 + c0];
            o1 += hv * w2l[c * 32 + c0 + 1];
        }
        unsigned short* op = XWt2 + (size_t)b * NC * NN + r0 + row;
        op[(size_t)c0 * NN]       = f2bf(o0);
        op[(size_t)(c0 + 1) * NN] = f2bf(o1);
    } else {
        if (w == 0) {
            const float bb0v = bias[lr], bb1v = bias[lr + 16];
            float s0 = 0.f, s1 = 0.f;
#pragma unroll
            for (int j = 0; j < 4; ++j) {
                const int row = kg * 4 + j;
                float a0 = acc0[j], a1 = acc1[j];
#pragma unroll
                for (int ww = 0; ww < 3; ++ww) {
                    a0 += red[ww][row][lr];
                    a1 += red[ww][row][lr + 16];
                }
                s0 += fmaxf(a0 + bb0v, 0.f);
                s1 += fmaxf(a1 + bb1v, 0.f);
            }
            // sum over the 4 row-groups (kg): lanes with same lr share the column
            s0 += __shfl_xor(s0, 16); s0 += __shfl_xor(s0, 32);
            s1 += __shfl_xor(s1, 16); s1 += __shfl_xor(s1, 32);
            if (kg == 0) {
                atomicAdd(&pooled[b * NC + lr],      s0);
                atomicAdd(&pooled[b * NC + 16 + lr], s1);
            }
        }
    }
}

// ---------------------------------------------------------------------------
// FC head: out[b] = sum_h relu(pooled[b,:] @ Wf1[:,h] + bf1[h]) * Wf2[h] + bf2
// ---------------------------------------------------------------------------
__global__ void head_kernel(const float* __restrict__ pooled,
                            const float* __restrict__ Wf1, const float* __restrict__ bf1,
                            const float* __restrict__ Wf2, const float* __restrict__ bf2,
                            float* __restrict__ out)
{
    const int b = blockIdx.x;
    const int h = threadIdx.x;   // 0..511

    float dot = 0.f;
#pragma unroll
    for (int c = 0; c < NC; ++c)
        dot += pooled[b * NC + c] * Wf1[c * 512 + h];

    const float v = fmaxf(dot + bf1[h], 0.f);
    float part    = v * Wf2[h];

#pragma unroll
    for (int off = 32; off >= 1; off >>= 1)
        part += __shfl_xor(part, off);

    __shared__ float redh[8];
    if ((threadIdx.x & 63) == 0) redh[threadIdx.x >> 6] = part;
    __syncthreads();
    if (threadIdx.x == 0) {
        float s = 0.f;
#pragma unroll
        for (int i = 0; i < 8; ++i) s += redh[i];
        out[b] = s + bf2[0];
    }
}

// ---------------------------------------------------------------------------
extern "C" void kernel_launch(void* const* d_in, const int* in_sizes, int n_in,
                              void* d_out, int out_size, void* d_ws, size_t ws_size,
                              hipStream_t stream)
{
    const float* x   = (const float*)d_in[0];
    const float* a   = (const float*)d_in[1];
    const float* W1  = (const float*)d_in[2];
    const float* b1  = (const float*)d_in[3];
    const float* W2  = (const float*)d_in[4];
    const float* b2  = (const float*)d_in[5];
    const float* Wf1 = (const float*)d_in[6];
    const float* bf1 = (const float*)d_in[7];
    const float* Wf2 = (const float*)d_in[8];
    const float* bf2 = (const float*)d_in[9];
    float* out = (float*)d_out;

    char* ws = (char*)d_ws;
    unsigned short* xwt1   = (unsigned short*)(ws);                 // 4 MB [b][c][m] bf16
    unsigned short* xwt2   = (unsigned short*)(ws + (4ull << 20));  // 4 MB [b][c][m] bf16
    float*          pooled = (float*)(ws + (8ull << 20));           // 4 KB [b][c] fp32

    hipMemsetAsync(pooled, 0, NB * NC * sizeof(float), stream);

    proj_kernel<64><<<dim3(NN / 256, NB), 256, 0, stream>>>(x, W1, xwt1);

    // L3-windowed pipeline: per 8-batch chunk (A-chunk 128MB), gemm1 streams A
    // from HBM; the immediately-following gemm2 re-reads it from Infinity Cache.
    for (int g = 0; g < NB / GB; ++g) {
        gcn_gemm_ks<true><<<dim3(NN / 16, GB), 256, 0, stream>>>(
            a, xwt1, b1, W2, xwt2, nullptr, g * GB);
        gcn_gemm_ks<false><<<dim3(NN / 16, GB), 256, 0, stream>>>(
            a, xwt2, b2, nullptr, nullptr, pooled, g * GB);
    }

    head_kernel<<<dim3(NB), 512, 0, stream>>>(pooled, Wf1, bf1, Wf2, bf2, out);
}

// Round 9
// 313.660 us; speedup vs baseline: 2.7036x; 1.0425x over previous
//
#include <hip/hip_runtime.h>
#include <hip/hip_bf16.h>

using bf16x8 = __attribute__((ext_vector_type(8))) short;
using f32x4  = __attribute__((ext_vector_type(4))) float;

static constexpr int NN = 2048;   // nodes
static constexpr int NB = 32;     // batch
static constexpr int NC = 32;     // channels (C1 == C2)

__device__ __forceinline__ unsigned short f2bf(float f) {
    unsigned int u = __float_as_uint(f);
    u += 0x7FFFu + ((u >> 16) & 1u);   // round-to-nearest-even
    return (unsigned short)(u >> 16);
}

// ---------------------------------------------------------------------------
// Projection: XWt[b][c][m] = bf16( sum_f X[b][m][f] * W[f][c] )   (no bias/relu)
// grid = (NN/256, NB), block = 256. One thread per node-row m.
// ---------------------------------------------------------------------------
template<int INCH>
__global__ void proj_kernel(const float* __restrict__ X, const float* __restrict__ W,
                            unsigned short* __restrict__ XWt)
{
    __shared__ float wlds[INCH * NC];
    const int b = blockIdx.y;
    const int m = blockIdx.x * 256 + threadIdx.x;
    for (int i = threadIdx.x; i < INCH * NC; i += 256) wlds[i] = W[i];
    __syncthreads();

    const float* xrow = X + ((size_t)b * NN + m) * INCH;
    float acc[NC];
#pragma unroll
    for (int c = 0; c < NC; ++c) acc[c] = 0.f;

    for (int f = 0; f < INCH; f += 4) {
        const float4 v = *reinterpret_cast<const float4*>(xrow + f);
        const float xv[4] = {v.x, v.y, v.z, v.w};
#pragma unroll
        for (int j = 0; j < 4; ++j) {
#pragma unroll
            for (int c = 0; c < NC; ++c)
                acc[c] += xv[j] * wlds[(f + j) * NC + c];
        }
    }

    unsigned short* outp = XWt + (size_t)b * NC * NN + m;
#pragma unroll
    for (int c = 0; c < NC; ++c) outp[(size_t)c * NN] = f2bf(acc[c]);
}

// ---------------------------------------------------------------------------
// GCN layer GEMM:  H = relu(A @ XW + bias).  grid=(NN/64, NB), 4 waves/block,
// each wave: 16 rows x 32 cols, full K.
// ABF=false: A read as fp32, converted in-register (v_cvt_pk_bf16_f32).
//   STORE16: additionally write the bf16 conversion to A16out ([b][row][k]
//   bf16, 64B-contiguous per 4-lane kg group) — gemm2 then re-reads A at
//   HALF the bytes. Read path caps at ~4.1 TB/s regardless of pattern or
//   L3 residency (rounds 1-8); writes ride the separate ~6.5 TB/s path.
// ABF=true: A read as bf16 from A16in (16B/lane per k-step, bit-identical
//   numerics to the in-register conversion).
// WRITE_H=true : write H fp32 [b][n][NC]  (layer 1)
// WRITE_H=false: relu + column-sum -> atomicAdd pooled  (layer 2 + pool)
// ---------------------------------------------------------------------------
template<bool WRITE_H, bool STORE16, bool ABF>
__global__ __launch_bounds__(256)
void gcn_gemm(const float* __restrict__ A, const unsigned short* __restrict__ A16in,
              unsigned short* __restrict__ A16out,
              const unsigned short* __restrict__ Bt, const float* __restrict__ bias,
              float* __restrict__ Hout, float* __restrict__ pooled)
{
    const int b    = blockIdx.y;
    const int wave = threadIdx.x >> 6;
    const int lane = threadIdx.x & 63;
    const int lr   = lane & 15;   // A-row / C-col index within tile
    const int kg   = lane >> 4;   // k-group (0..3), 8 k-elements each

    const int r0  = blockIdx.x * 64 + wave * 16;
    const int row = r0 + lr;

    const float*          ap   = A     + ((size_t)b * NN + row) * NN + kg * 8;
    const unsigned short* ap16 = A16in + ((size_t)b * NN + row) * NN + kg * 8;
    unsigned short*       sp16 = STORE16 ? (A16out + ((size_t)b * NN + row) * NN + kg * 8)
                                         : nullptr;
    const unsigned short* bp0  = Bt + ((size_t)b * NC + lr) * NN + kg * 8;
    const unsigned short* bp1  = bp0 + (size_t)16 * NN;

    f32x4 acc0 = {0.f, 0.f, 0.f, 0.f};
    f32x4 acc1 = {0.f, 0.f, 0.f, 0.f};
    union ABf { bf16x8 v; __hip_bfloat16 e[8]; };

#pragma unroll 4
    for (int k = 0; k < NN; k += 32) {
        const bf16x8 bv0 = *reinterpret_cast<const bf16x8*>(bp0 + k);
        const bf16x8 bv1 = *reinterpret_cast<const bf16x8*>(bp1 + k);

        bf16x8 av;
        if constexpr (ABF) {
            av = *reinterpret_cast<const bf16x8*>(ap16 + k);
        } else {
            const float4 x0 = *reinterpret_cast<const float4*>(ap + k);
            const float4 x1 = *reinterpret_cast<const float4*>(ap + k + 4);
            ABf af;
            af.e[0] = __float2bfloat16(x0.x); af.e[1] = __float2bfloat16(x0.y);
            af.e[2] = __float2bfloat16(x0.z); af.e[3] = __float2bfloat16(x0.w);
            af.e[4] = __float2bfloat16(x1.x); af.e[5] = __float2bfloat16(x1.y);
            af.e[6] = __float2bfloat16(x1.z); af.e[7] = __float2bfloat16(x1.w);
            av = af.v;
            if constexpr (STORE16)
                *reinterpret_cast<bf16x8*>(sp16 + k) = av;
        }

        acc0 = __builtin_amdgcn_mfma_f32_16x16x32_bf16(av, bv0, acc0, 0, 0, 0);
        acc1 = __builtin_amdgcn_mfma_f32_16x16x32_bf16(av, bv1, acc1, 0, 0, 0);
    }

    const float bias0 = bias[lr];
    const float bias1 = bias[lr + 16];

    if constexpr (WRITE_H) {
#pragma unroll
        for (int j = 0; j < 4; ++j) {
            const int rr = r0 + kg * 4 + j;
            float* hp = Hout + ((size_t)b * NN + rr) * NC;
            hp[lr]      = fmaxf(acc0[j] + bias0, 0.f);
            hp[lr + 16] = fmaxf(acc1[j] + bias1, 0.f);
        }
    } else {
        float s0 = 0.f, s1 = 0.f;
#pragma unroll
        for (int j = 0; j < 4; ++j) {
            s0 += fmaxf(acc0[j] + bias0, 0.f);
            s1 += fmaxf(acc1[j] + bias1, 0.f);
        }
        // reduce over the 4 row-groups (lane bits 4,5): lanes with same lr share col
        s0 += __shfl_xor(s0, 16); s0 += __shfl_xor(s0, 32);
        s1 += __shfl_xor(s1, 16); s1 += __shfl_xor(s1, 32);
        if (kg == 0) {
            atomicAdd(&pooled[b * NC + lr],      s0);
            atomicAdd(&pooled[b * NC + 16 + lr], s1);
        }
    }
}

// ---------------------------------------------------------------------------
// FC head: out[b] = sum_h relu(pooled[b,:] @ Wf1[:,h] + bf1[h]) * Wf2[h] + bf2
// ---------------------------------------------------------------------------
__global__ void head_kernel(const float* __restrict__ pooled,
                            const float* __restrict__ Wf1, const float* __restrict__ bf1,
                            const float* __restrict__ Wf2, const float* __restrict__ bf2,
                            float* __restrict__ out)
{
    const int b = blockIdx.x;
    const int h = threadIdx.x;   // 0..511

    float dot = 0.f;
#pragma unroll
    for (int c = 0; c < NC; ++c)
        dot += pooled[b * NC + c] * Wf1[c * 512 + h];

    const float v = fmaxf(dot + bf1[h], 0.f);
    float part    = v * Wf2[h];

#pragma unroll
    for (int off = 32; off >= 1; off >>= 1)
        part += __shfl_xor(part, off);

    __shared__ float red[8];
    if ((threadIdx.x & 63) == 0) red[threadIdx.x >> 6] = part;
    __syncthreads();
    if (threadIdx.x == 0) {
        float s = 0.f;
#pragma unroll
        for (int i = 0; i < 8; ++i) s += red[i];
        out[b] = s + bf2[0];
    }
}

// ---------------------------------------------------------------------------
extern "C" void kernel_launch(void* const* d_in, const int* in_sizes, int n_in,
                              void* d_out, int out_size, void* d_ws, size_t ws_size,
                              hipStream_t stream)
{
    const float* x   = (const float*)d_in[0];
    const float* a   = (const float*)d_in[1];
    const float* W1  = (const float*)d_in[2];
    const float* b1  = (const float*)d_in[3];
    const float* W2  = (const float*)d_in[4];
    const float* b2  = (const float*)d_in[5];
    const float* Wf1 = (const float*)d_in[6];
    const float* bf1 = (const float*)d_in[7];
    const float* Wf2 = (const float*)d_in[8];
    const float* bf2 = (const float*)d_in[9];
    float* out = (float*)d_out;

    const size_t A16_BYTES = (size_t)NB * NN * NN * 2;   // 256 MB
    char* ws = (char*)d_ws;

    if (ws_size >= A16_BYTES + (20ull << 20)) {
        // ---- bf16 A-recycle path ----
        unsigned short* A16    = (unsigned short*)(ws);
        unsigned short* xwt1   = (unsigned short*)(ws + A16_BYTES);
        unsigned short* xwt2   = (unsigned short*)(ws + A16_BYTES + (4ull << 20));
        float*          h1     = (float*)(ws + A16_BYTES + (8ull << 20));
        float*          pooled = (float*)(ws + A16_BYTES + (16ull << 20));

        hipMemsetAsync(pooled, 0, NB * NC * sizeof(float), stream);

        proj_kernel<64><<<dim3(NN / 256, NB), 256, 0, stream>>>(x, W1, xwt1);

        // layer 1: read A fp32 (512MB), emit bf16(A) (256MB) for reuse
        gcn_gemm<true, true, false><<<dim3(NN / 64, NB), 256, 0, stream>>>(
            a, nullptr, A16, xwt1, b1, h1, nullptr);

        proj_kernel<32><<<dim3(NN / 256, NB), 256, 0, stream>>>(h1, W2, xwt2);

        // layer 2: read A as bf16 (256MB) — half the read bytes
        gcn_gemm<false, false, true><<<dim3(NN / 64, NB), 256, 0, stream>>>(
            nullptr, A16, nullptr, xwt2, b2, nullptr, pooled);

        head_kernel<<<dim3(NB), 512, 0, stream>>>(pooled, Wf1, bf1, Wf2, bf2, out);
    } else {
        // ---- fallback: proven round-5 structure (no A16 workspace) ----
        unsigned short* xwt1   = (unsigned short*)(ws);
        unsigned short* xwt2   = (unsigned short*)(ws + (4ull << 20));
        float*          h1     = (float*)(ws + (8ull << 20));
        float*          pooled = (float*)(ws + (16ull << 20));

        hipMemsetAsync(pooled, 0, NB * NC * sizeof(float), stream);

        proj_kernel<64><<<dim3(NN / 256, NB), 256, 0, stream>>>(x, W1, xwt1);
        gcn_gemm<true, false, false><<<dim3(NN / 64, NB), 256, 0, stream>>>(
            a, nullptr, nullptr, xwt1, b1, h1, nullptr);
        proj_kernel<32><<<dim3(NN / 256, NB), 256, 0, stream>>>(h1, W2, xwt2);
        gcn_gemm<false, false, false><<<dim3(NN / 64, NB), 256, 0, stream>>>(
            a, nullptr, nullptr, xwt2, b2, nullptr, pooled);
        head_kernel<<<dim3(NB), 512, 0, stream>>>(pooled, Wf1, bf1, Wf2, bf2, out);
    }
}